// Round 1
// 89.455 us; speedup vs baseline: 1.0664x; 1.0664x over previous
//
#include <hip/hip_runtime.h>

// PiecewiseSparseMLP: B=262144 rows, K=32 experts (10 -> 20 -> 1), distance-softmax gating.
// Round 17: DENSE hidden packing. Instead of one MFMA per expert (20/32 M-rows used,
// cross-half pred exchange every iteration), MFMA jj computes hidden unit jj of ALL 32
// experts (M-row m = expert m; mapping inverts to e(m)=m exactly). Consequences:
//   - 20 full-density MFMAs + 1 gating MFMA per tile (was 33)
//   - c[q] is expert-ordered IDENTICALLY to the gating MFMA output -> per-lane
//     pacc[q] += relu(c[q]) * W2[p(q,half)][jj] needs NO cross-lane traffic; the only
//     swizzles left are the final nsum/dsum xor-32 merges.
//   - gating deferred to the epilogue: gates consumed on the fly (no gate[2][16] array
//     live through the main loop -> ~32 VGPRs freed, pays for pacc[2][8]).
//   - b2 folded via {||proto||^2, b2} float2 table read in the gating fold.
// Proven-stable pattern kept: block=512, launch_bounds(512,4)=cap 128, `unroll 2`,
// statically indexed arrays only (R8/R9/R15 spill lessons). grid=512.

#define KX 32
#define DIN 10
#define DH 20
#define BLOCK 512
#define WPB 8   // waves per block
#define TPW 2   // row-tiles per wave (interleaved)

typedef short bf16x8 __attribute__((ext_vector_type(8)));
typedef float f32x16 __attribute__((ext_vector_type(16)));
typedef float v2f    __attribute__((ext_vector_type(2)));

#define ZERO16 {0.f,0.f,0.f,0.f, 0.f,0.f,0.f,0.f, 0.f,0.f,0.f,0.f, 0.f,0.f,0.f,0.f}

__device__ inline unsigned short f2bf(float f) {   // fp32 -> bf16 RNE
    unsigned int u = __float_as_uint(f);
    unsigned int r = u + 0x7fffu + ((u >> 16) & 1u);
    return (unsigned short)(r >> 16);
}

union BFU { bf16x8 v; unsigned short s[8]; };

__global__ __launch_bounds__(BLOCK, 4) void moe_kernel(
    const float* __restrict__ x,      // [B,10]
    const float* __restrict__ W1,     // [32,20,10]
    const float* __restrict__ b1,     // [32,20]
    const float* __restrict__ W2,     // [32,1,20]
    const float* __restrict__ b2,     // [32]
    const float* __restrict__ proto,  // [32,10]
    float* __restrict__ out,          // [B]
    int B)
{
    // A-frags: [jj][e*2 + ks] -> W1[e][jj][ks*8..+7] (k=10 slot = b1, rest 0). 20 KB.
    __shared__ bf16x8 s_af2[DH * 64];
    // W2 in C-reg order: [jj][hf*16 + q] = W2[p(q,hf)][jj]. 2.5 KB, 16B-aligned for float4.
    __shared__ __attribute__((aligned(16))) float s_w2c[DH * 32];
    __shared__ bf16x8 s_pf[64];        // proto A-frag (1 KB)
    __shared__ float2 s_gk[32];        // {||proto||^2, b2} in [hf*16+q] order

    const int tid = threadIdx.x;

    // ---- build LDS tables (shared by all 8 waves, amortized over 2 tiles/wave) ----
    for (int idx = tid; idx < DH * 64; idx += BLOCK) {
        const int jj = idx >> 6, rem = idx & 63;
        const int e = rem >> 1, ks = rem & 1;
        BFU u;
#pragma unroll
        for (int j = 0; j < 8; ++j) {
            const int kk = ks * 8 + j;
            float v = 0.f;
            if (kk < DIN) v = W1[(e * DH + jj) * DIN + kk];
            else if (kk == DIN) v = b1[e * DH + jj];   // bias slot (x_ext[10]=1)
            u.s[j] = f2bf(v);
        }
        s_af2[idx] = u.v;
    }
    for (int idx = tid; idx < DH * 32; idx += BLOCK) {
        const int jj = idx >> 5, rem = idx & 31;
        const int hf = rem >> 4, q = rem & 15;
        const int p = (q & 3) + 8 * (q >> 2) + 4 * hf;   // expert of C-reg q in half hf
        s_w2c[idx] = W2[p * DH + jj];
    }
    if (tid < 64) {
        const int m = tid & 31, kb = (tid >> 5) * 8;
        BFU u;
#pragma unroll
        for (int j = 0; j < 8; ++j) {
            const int kk = kb + j;
            u.s[j] = f2bf(kk < DIN ? proto[m * DIN + kk] : 0.f);  // slot 10 = 0
        }
        s_pf[tid] = u.v;
    }
    if (tid < 32) {
        const int hf = tid >> 4, q = tid & 15;
        const int p = (q & 3) + 8 * (q >> 2) + 4 * hf;
        float s = 0.f;
#pragma unroll
        for (int i = 0; i < DIN; ++i) { const float v = proto[p * DIN + i]; s = fmaf(v, v, s); }
        s_gk[tid] = make_float2(s, b2[p]);
    }
    __syncthreads();

    const int lane = tid & 63;
    const int wave = tid >> 6;
    const int half = lane >> 5;   // k-slice for A/B frags; C-half for epilogue
    const int col  = lane & 31;
    const bf16x8 pfrag = s_pf[lane];
    const f32x16 kZero = ZERO16;
    const int aoff = (col << 1) + half;   // lane's A-frag slot within each jj block

    // ---- per-tile state (statically indexed only) ----
    int    row[TPW];
    bf16x8 xfrag[TPW];
    float  xn2[TPW];
    v2f    pa[TPW][8];   // per-lane pred partials, expert-ordered like gate regs

#pragma unroll
    for (int t = 0; t < TPW; ++t) {
        row[t] = ((blockIdx.x * WPB + wave) * TPW + t) * 32 + col;
        const int rr = (row[t] < B) ? row[t] : (B - 1);

        // B-frag: x_ext[rr][half*8 .. +7]; slot 10 = 1.0 (bias)
        float xe[8];
        const float* xr = x + (size_t)rr * DIN;
        if (half == 0) {
#pragma unroll
            for (int i = 0; i < 4; ++i) {
                const float2 v = *(const float2*)(xr + 2 * i);
                xe[2 * i] = v.x; xe[2 * i + 1] = v.y;
            }
        } else {
            const float2 v = *(const float2*)(xr + 8);
            xe[0] = v.x; xe[1] = v.y; xe[2] = 1.f;
            xe[3] = 0.f; xe[4] = 0.f; xe[5] = 0.f; xe[6] = 0.f; xe[7] = 0.f;
        }
        BFU xu;
#pragma unroll
        for (int j = 0; j < 8; ++j) xu.s[j] = f2bf(xe[j]);
        xfrag[t] = xu.v;

        // ||x||^2 (fp32): half0 sums its 8, half1 only x[8],x[9]
        float part;
        if (half == 0) {
            part = 0.f;
#pragma unroll
            for (int j = 0; j < 8; ++j) part = fmaf(xe[j], xe[j], part);
        } else {
            part = fmaf(xe[0], xe[0], xe[1] * xe[1]);
        }
        xn2[t] = part + __shfl_xor(part, 32);

#pragma unroll
        for (int i = 0; i < 8; ++i) pa[t][i] = v2f{0.f, 0.f};
    }

    // ---- dense main loop: MFMA jj = hidden unit jj of ALL 32 experts (e(m)=m) ----
    const float4* w2base = (const float4*)s_w2c + (half << 2);
#pragma unroll 2
    for (int jj = 0; jj < DH; ++jj) {
        const bf16x8 a = s_af2[(jj << 6) + aoff];
        const float4* w4 = w2base + (jj << 3);
        const float4 w0 = w4[0], w1v = w4[1], w2v = w4[2], w3v = w4[3];

#pragma unroll
        for (int t = 0; t < TPW; ++t) {
            const f32x16 c = __builtin_amdgcn_mfma_f32_32x32x16_bf16(a, xfrag[t], kZero, 0, 0, 0);
            v2f r;
            r = __builtin_elementwise_max(v2f{c[0],  c[1]},  v2f{0.f, 0.f});
            pa[t][0] = __builtin_elementwise_fma(r, v2f{w0.x,  w0.y},  pa[t][0]);
            r = __builtin_elementwise_max(v2f{c[2],  c[3]},  v2f{0.f, 0.f});
            pa[t][1] = __builtin_elementwise_fma(r, v2f{w0.z,  w0.w},  pa[t][1]);
            r = __builtin_elementwise_max(v2f{c[4],  c[5]},  v2f{0.f, 0.f});
            pa[t][2] = __builtin_elementwise_fma(r, v2f{w1v.x, w1v.y}, pa[t][2]);
            r = __builtin_elementwise_max(v2f{c[6],  c[7]},  v2f{0.f, 0.f});
            pa[t][3] = __builtin_elementwise_fma(r, v2f{w1v.z, w1v.w}, pa[t][3]);
            r = __builtin_elementwise_max(v2f{c[8],  c[9]},  v2f{0.f, 0.f});
            pa[t][4] = __builtin_elementwise_fma(r, v2f{w2v.x, w2v.y}, pa[t][4]);
            r = __builtin_elementwise_max(v2f{c[10], c[11]}, v2f{0.f, 0.f});
            pa[t][5] = __builtin_elementwise_fma(r, v2f{w2v.z, w2v.w}, pa[t][5]);
            r = __builtin_elementwise_max(v2f{c[12], c[13]}, v2f{0.f, 0.f});
            pa[t][6] = __builtin_elementwise_fma(r, v2f{w3v.x, w3v.y}, pa[t][6]);
            r = __builtin_elementwise_max(v2f{c[14], c[15]}, v2f{0.f, 0.f});
            pa[t][7] = __builtin_elementwise_fma(r, v2f{w3v.z, w3v.w}, pa[t][7]);
        }
    }

    // ---- deferred gating + combine + write (both tiles) ----
    const float2* gkh = s_gk + half * 16;
#pragma unroll
    for (int t = 0; t < TPW; ++t) {
        const f32x16 dg = __builtin_amdgcn_mfma_f32_32x32x16_bf16(pfrag, xfrag[t], kZero, 0, 0, 0);
        float ds = 0.f, ns = 0.f;
#pragma unroll
        for (int q = 0; q < 16; ++q) {
            const float2 gk = gkh[q];
            float d2 = fmaf(dg[q], -2.f, xn2[t] + gk.x);
            d2 = fmaxf(d2, 0.f);
            const float g = __expf(-__fsqrt_rn(d2));
            ds += g;
            const v2f pp = pa[t][q >> 1];
            const float pq = (q & 1) ? pp.y : pp.x;
            ns = fmaf(g, pq + gk.y, ns);   // gate * (pred_partial + b2)
        }
        const float nst = ns + __shfl_xor(ns, 32);
        const float dst = ds + __shfl_xor(ds, 32);
        if (half == 0 && row[t] < B) out[row[t]] = nst / dst;
    }
}

extern "C" void kernel_launch(void* const* d_in, const int* in_sizes, int n_in,
                              void* d_out, int out_size, void* d_ws, size_t ws_size,
                              hipStream_t stream) {
    const float* x     = (const float*)d_in[0];
    const float* W1    = (const float*)d_in[1];
    const float* b1    = (const float*)d_in[2];
    const float* W2    = (const float*)d_in[3];
    const float* b2    = (const float*)d_in[4];
    const float* proto = (const float*)d_in[5];
    float* out = (float*)d_out;

    const int B = out_size;                    // D_OUT = 1
    const int rows_per_block = WPB * TPW * 32; // 8 waves x 2 tiles x 32 rows = 512
    const int grid = (B + rows_per_block - 1) / rows_per_block;
    hipLaunchKernelGGL(moe_kernel, dim3(grid), dim3(BLOCK), 0, stream,
                       x, W1, b1, W2, b2, proto, out, B);
}

// Round 2
// 88.860 us; speedup vs baseline: 1.0736x; 1.0067x over previous
//
#include <hip/hip_runtime.h>

// PiecewiseSparseMLP: B=262144 rows, K=32 experts (10 -> 20 -> 1), distance-softmax gating.
// Round 18: R17 dense-hidden structure (MFMA jj = hidden unit jj of all 32 experts,
// e(m)=m, gate-aligned C regs, deferred gating) + consolidated VALU trims OUTSIDE the
// main loop (main loop is at its 1.5-instr/element floor: no packed f32 max on CDNA4):
//   - BLOCK 1024 (16 waves share one LDS build; was 8) -> build cost/wave halves.
//   - exp2 fold: d2 pre-scaled by (log2 e)^2 so gate = v_exp_f32(-sqrt(d2')) with no
//     per-gate v_mul (e^-d == 2^(-d*log2e), sqrt absorbs the scale).
//   - b2 folded into pa[] init (each expert lives in exactly one half -> no double
//     count) -> kills the per-q "+b2" add in the epilogue.
//   - final divide via v_rcp (softmax denom > 0; ~1e-7 rel err << 0.0039 absmax).
// Proven-stable pattern kept: launch_bounds cap 128, `unroll 2`, statically indexed
// arrays only (R8/R9/R15 spill lessons). grid=256.

#define KX 32
#define DIN 10
#define DH 20
#define BLOCK 1024
#define WPB 16  // waves per block
#define TPW 2   // row-tiles per wave (interleaved)

#define LOG2E_SQ 2.0813689810056077f
#define NEG2_LOG2E_SQ -4.1627379620112154f

typedef short bf16x8 __attribute__((ext_vector_type(8)));
typedef float f32x16 __attribute__((ext_vector_type(16)));
typedef float v2f    __attribute__((ext_vector_type(2)));

#define ZERO16 {0.f,0.f,0.f,0.f, 0.f,0.f,0.f,0.f, 0.f,0.f,0.f,0.f, 0.f,0.f,0.f,0.f}

__device__ inline unsigned short f2bf(float f) {   // fp32 -> bf16 RNE
    unsigned int u = __float_as_uint(f);
    unsigned int r = u + 0x7fffu + ((u >> 16) & 1u);
    return (unsigned short)(r >> 16);
}

union BFU { bf16x8 v; unsigned short s[8]; };

__global__ __launch_bounds__(BLOCK, 4) void moe_kernel(
    const float* __restrict__ x,      // [B,10]
    const float* __restrict__ W1,     // [32,20,10]
    const float* __restrict__ b1,     // [32,20]
    const float* __restrict__ W2,     // [32,1,20]
    const float* __restrict__ b2,     // [32]
    const float* __restrict__ proto,  // [32,10]
    float* __restrict__ out,          // [B]
    int B)
{
    // A-frags: [jj][e*2 + ks] -> W1[e][jj][ks*8..+7] (k=10 slot = b1, rest 0). 20 KB.
    __shared__ bf16x8 s_af2[DH * 64];
    // W2 in C-reg order: [jj][hf*16 + q] = W2[p(q,hf)][jj]. 2.5 KB, 16B-aligned.
    __shared__ __attribute__((aligned(16))) float s_w2c[DH * 32];
    __shared__ bf16x8 s_pf[64];        // proto A-frag (1 KB)
    __shared__ float  s_gk[32];        // ||proto||^2 * (log2 e)^2 in [hf*16+q] order
    __shared__ float2 s_b2p[16];       // b2 pairs in [hf*8+i] order (pa init)

    const int tid = threadIdx.x;

    // ---- build LDS tables (shared by all 16 waves, amortized over 2 tiles/wave) ----
    for (int idx = tid; idx < DH * 64; idx += BLOCK) {
        const int jj = idx >> 6, rem = idx & 63;
        const int e = rem >> 1, ks = rem & 1;
        BFU u;
#pragma unroll
        for (int j = 0; j < 8; ++j) {
            const int kk = ks * 8 + j;
            float v = 0.f;
            if (kk < DIN) v = W1[(e * DH + jj) * DIN + kk];
            else if (kk == DIN) v = b1[e * DH + jj];   // bias slot (x_ext[10]=1)
            u.s[j] = f2bf(v);
        }
        s_af2[idx] = u.v;
    }
    for (int idx = tid; idx < DH * 32; idx += BLOCK) {
        const int jj = idx >> 5, rem = idx & 31;
        const int hf = rem >> 4, q = rem & 15;
        const int p = (q & 3) + 8 * (q >> 2) + 4 * hf;   // expert of C-reg q in half hf
        s_w2c[idx] = W2[p * DH + jj];
    }
    if (tid < 64) {
        const int m = tid & 31, kb = (tid >> 5) * 8;
        BFU u;
#pragma unroll
        for (int j = 0; j < 8; ++j) {
            const int kk = kb + j;
            u.s[j] = f2bf(kk < DIN ? proto[m * DIN + kk] : 0.f);  // slot 10 = 0
        }
        s_pf[tid] = u.v;
    }
    if (tid < 32) {
        const int hf = tid >> 4, q = tid & 15;
        const int p = (q & 3) + 8 * (q >> 2) + 4 * hf;
        float s = 0.f;
#pragma unroll
        for (int i = 0; i < DIN; ++i) { const float v = proto[p * DIN + i]; s = fmaf(v, v, s); }
        s_gk[tid] = s * LOG2E_SQ;
    }
    if (tid < 16) {
        const int hf = tid >> 3, i = tid & 7;
        const int q0 = 2 * i, q1 = 2 * i + 1;
        const int p0 = (q0 & 3) + 8 * (q0 >> 2) + 4 * hf;
        const int p1 = (q1 & 3) + 8 * (q1 >> 2) + 4 * hf;
        s_b2p[tid] = make_float2(b2[p0], b2[p1]);
    }
    __syncthreads();

    const int lane = tid & 63;
    const int wave = tid >> 6;
    const int half = lane >> 5;   // k-slice for A/B frags; C-half for epilogue
    const int col  = lane & 31;
    const bf16x8 pfrag = s_pf[lane];
    const f32x16 kZero = ZERO16;
    const int aoff = (col << 1) + half;   // lane's A-frag slot within each jj block

    // ---- per-tile state (statically indexed only) ----
    int    row[TPW];
    bf16x8 xfrag[TPW];
    float  xn2[TPW];     // ||x||^2 * (log2 e)^2
    v2f    pa[TPW][8];   // per-lane pred partials (b2 pre-loaded), gate-reg-ordered

#pragma unroll
    for (int t = 0; t < TPW; ++t) {
        row[t] = ((blockIdx.x * WPB + wave) * TPW + t) * 32 + col;
        const int rr = (row[t] < B) ? row[t] : (B - 1);

        // B-frag: x_ext[rr][half*8 .. +7]; slot 10 = 1.0 (bias)
        float xe[8];
        const float* xr = x + (size_t)rr * DIN;
        if (half == 0) {
#pragma unroll
            for (int i = 0; i < 4; ++i) {
                const float2 v = *(const float2*)(xr + 2 * i);
                xe[2 * i] = v.x; xe[2 * i + 1] = v.y;
            }
        } else {
            const float2 v = *(const float2*)(xr + 8);
            xe[0] = v.x; xe[1] = v.y; xe[2] = 1.f;
            xe[3] = 0.f; xe[4] = 0.f; xe[5] = 0.f; xe[6] = 0.f; xe[7] = 0.f;
        }
        BFU xu;
#pragma unroll
        for (int j = 0; j < 8; ++j) xu.s[j] = f2bf(xe[j]);
        xfrag[t] = xu.v;

        // ||x||^2 (fp32): half0 sums its 8, half1 only x[8],x[9]; pre-scale by c^2
        float part;
        if (half == 0) {
            part = 0.f;
#pragma unroll
            for (int j = 0; j < 8; ++j) part = fmaf(xe[j], xe[j], part);
        } else {
            part = fmaf(xe[0], xe[0], xe[1] * xe[1]);
        }
        xn2[t] = (part + __shfl_xor(part, 32)) * LOG2E_SQ;

#pragma unroll
        for (int i = 0; i < 8; ++i) {
            const float2 bp = s_b2p[half * 8 + i];
            pa[t][i] = v2f{bp.x, bp.y};
        }
    }

    // ---- dense main loop: MFMA jj = hidden unit jj of ALL 32 experts (e(m)=m) ----
    const float4* w2base = (const float4*)s_w2c + (half << 2);
#pragma unroll 2
    for (int jj = 0; jj < DH; ++jj) {
        const bf16x8 a = s_af2[(jj << 6) + aoff];
        const float4* w4 = w2base + (jj << 3);
        const float4 w0 = w4[0], w1v = w4[1], w2v = w4[2], w3v = w4[3];

#pragma unroll
        for (int t = 0; t < TPW; ++t) {
            const f32x16 c = __builtin_amdgcn_mfma_f32_32x32x16_bf16(a, xfrag[t], kZero, 0, 0, 0);
            v2f r;
            r = __builtin_elementwise_max(v2f{c[0],  c[1]},  v2f{0.f, 0.f});
            pa[t][0] = __builtin_elementwise_fma(r, v2f{w0.x,  w0.y},  pa[t][0]);
            r = __builtin_elementwise_max(v2f{c[2],  c[3]},  v2f{0.f, 0.f});
            pa[t][1] = __builtin_elementwise_fma(r, v2f{w0.z,  w0.w},  pa[t][1]);
            r = __builtin_elementwise_max(v2f{c[4],  c[5]},  v2f{0.f, 0.f});
            pa[t][2] = __builtin_elementwise_fma(r, v2f{w1v.x, w1v.y}, pa[t][2]);
            r = __builtin_elementwise_max(v2f{c[6],  c[7]},  v2f{0.f, 0.f});
            pa[t][3] = __builtin_elementwise_fma(r, v2f{w1v.z, w1v.w}, pa[t][3]);
            r = __builtin_elementwise_max(v2f{c[8],  c[9]},  v2f{0.f, 0.f});
            pa[t][4] = __builtin_elementwise_fma(r, v2f{w2v.x, w2v.y}, pa[t][4]);
            r = __builtin_elementwise_max(v2f{c[10], c[11]}, v2f{0.f, 0.f});
            pa[t][5] = __builtin_elementwise_fma(r, v2f{w2v.z, w2v.w}, pa[t][5]);
            r = __builtin_elementwise_max(v2f{c[12], c[13]}, v2f{0.f, 0.f});
            pa[t][6] = __builtin_elementwise_fma(r, v2f{w3v.x, w3v.y}, pa[t][6]);
            r = __builtin_elementwise_max(v2f{c[14], c[15]}, v2f{0.f, 0.f});
            pa[t][7] = __builtin_elementwise_fma(r, v2f{w3v.z, w3v.w}, pa[t][7]);
        }
    }

    // ---- deferred gating + combine + write (both tiles) ----
    const float* gkx = s_gk + half * 16;
#pragma unroll
    for (int t = 0; t < TPW; ++t) {
        const f32x16 dg = __builtin_amdgcn_mfma_f32_32x32x16_bf16(pfrag, xfrag[t], kZero, 0, 0, 0);
        float ds = 0.f, ns = 0.f;
#pragma unroll
        for (int q = 0; q < 16; ++q) {
            float d2 = fmaf(dg[q], NEG2_LOG2E_SQ, xn2[t] + gkx[q]);
            d2 = fmaxf(d2, 0.f);
            const float g = __builtin_amdgcn_exp2f(-__fsqrt_rn(d2));
            ds += g;
            const v2f pp = pa[t][q >> 1];
            const float pq = (q & 1) ? pp.y : pp.x;
            ns = fmaf(g, pq, ns);   // b2 already inside pa
        }
        const float nst = ns + __shfl_xor(ns, 32);
        const float dst = ds + __shfl_xor(ds, 32);
        if (half == 0 && row[t] < B) out[row[t]] = nst * __builtin_amdgcn_rcpf(dst);
    }
}

extern "C" void kernel_launch(void* const* d_in, const int* in_sizes, int n_in,
                              void* d_out, int out_size, void* d_ws, size_t ws_size,
                              hipStream_t stream) {
    const float* x     = (const float*)d_in[0];
    const float* W1    = (const float*)d_in[1];
    const float* b1    = (const float*)d_in[2];
    const float* W2    = (const float*)d_in[3];
    const float* b2    = (const float*)d_in[4];
    const float* proto = (const float*)d_in[5];
    float* out = (float*)d_out;

    const int B = out_size;                    // D_OUT = 1
    const int rows_per_block = WPB * TPW * 32; // 16 waves x 2 tiles x 32 rows = 1024
    const int grid = (B + rows_per_block - 1) / rows_per_block;
    hipLaunchKernelGGL(moe_kernel, dim3(grid), dim3(BLOCK), 0, stream,
                       x, W1, b1, W2, b2, proto, out, B);
}

// Round 3
// 86.723 us; speedup vs baseline: 1.1000x; 1.0246x over previous
//
#include <hip/hip_runtime.h>

// PiecewiseSparseMLP: B=262144 rows, K=32 experts (10 -> 20 -> 1), distance-softmax gating.
// Round 19: R18 structure (dense hidden packing: MFMA jj = hidden unit jj of all 32
// experts, e(m)=m, gate-aligned C regs, deferred gating, exp2/rcp folds) + last
// VALU/latency trims OUTSIDE the main loop (main loop at 1.5-instr/elem floor):
//   - pk-ized epilogue: gate pairs via v_pk_add/v_pk_fma (gk table as float2);
//     10 instr/pair vs 14 (transcendentals unchanged).
//   - static-ks W1 build: ks=0 loop uses 4x float2 contiguous loads (no per-element
//     bounds branches), ks=1 loop loads {x8,x9,b1} directly. ~Halves build VALU+loads.
//   - x row loads issued BEFORE the LDS build (compiler can't hoist across barrier);
//     ~500cy global latency hides under table construction.
// Proven-stable: launch_bounds(1024,4)=cap 128, `unroll 2`, statically indexed arrays
// only (R8/R9/R15 spill lessons). grid=256.

#define KX 32
#define DIN 10
#define DH 20
#define BLOCK 1024
#define WPB 16  // waves per block
#define TPW 2   // row-tiles per wave (interleaved)

#define LOG2E_SQ 2.0813689810056077f
#define NEG2_LOG2E_SQ -4.1627379620112154f

typedef short bf16x8 __attribute__((ext_vector_type(8)));
typedef float f32x16 __attribute__((ext_vector_type(16)));
typedef float v2f    __attribute__((ext_vector_type(2)));

#define ZERO16 {0.f,0.f,0.f,0.f, 0.f,0.f,0.f,0.f, 0.f,0.f,0.f,0.f, 0.f,0.f,0.f,0.f}

__device__ inline unsigned short f2bf(float f) {   // fp32 -> bf16 RNE
    unsigned int u = __float_as_uint(f);
    unsigned int r = u + 0x7fffu + ((u >> 16) & 1u);
    return (unsigned short)(r >> 16);
}

union BFU { bf16x8 v; unsigned short s[8]; };

__global__ __launch_bounds__(BLOCK, 4) void moe_kernel(
    const float* __restrict__ x,      // [B,10]
    const float* __restrict__ W1,     // [32,20,10]
    const float* __restrict__ b1,     // [32,20]
    const float* __restrict__ W2,     // [32,1,20]
    const float* __restrict__ b2,     // [32]
    const float* __restrict__ proto,  // [32,10]
    float* __restrict__ out,          // [B]
    int B)
{
    // A-frags: [jj][e*2 + ks] -> W1[e][jj][ks*8..+7] (k=10 slot = b1, rest 0). 20 KB.
    __shared__ bf16x8 s_af2[DH * 64];
    // W2 in C-reg order: [jj][hf*16 + q] = W2[p(q,hf)][jj]. 2.5 KB, 16B-aligned.
    __shared__ __attribute__((aligned(16))) float s_w2c[DH * 32];
    __shared__ bf16x8 s_pf[64];        // proto A-frag (1 KB)
    __shared__ float2 s_gkp[16];       // ||proto||^2*(log2e)^2 PAIRS, [hf*8+i] order
    __shared__ float2 s_b2p[16];       // b2 pairs in [hf*8+i] order (pa init)

    const int tid  = threadIdx.x;
    const int lane = tid & 63;
    const int wave = tid >> 6;
    const int half = lane >> 5;   // k-slice for A/B frags; C-half for epilogue
    const int col  = lane & 31;

    // ---- issue x row loads FIRST (latency hides under the LDS table build) ----
    int    row[TPW];
    float2 xld[TPW][4];   // half0 uses all 4; half1 uses [0] only
#pragma unroll
    for (int t = 0; t < TPW; ++t) {
        row[t] = ((blockIdx.x * WPB + wave) * TPW + t) * 32 + col;
        const int rr = (row[t] < B) ? row[t] : (B - 1);
        const float* xr = x + (size_t)rr * DIN;
        if (half == 0) {
#pragma unroll
            for (int i = 0; i < 4; ++i) xld[t][i] = *(const float2*)(xr + 2 * i);
        } else {
            xld[t][0] = *(const float2*)(xr + 8);
        }
    }

    // ---- build LDS tables (shared by all 16 waves) ----
    // ks=0 half of each A-frag pair: 8 contiguous floats, static bounds.
    for (int ii = tid; ii < DH * 32; ii += BLOCK) {
        const int jj = ii >> 5, e = ii & 31;
        const float* wr = W1 + (size_t)(e * DH + jj) * DIN;
        BFU u;
#pragma unroll
        for (int i = 0; i < 4; ++i) {
            const float2 v = *(const float2*)(wr + 2 * i);
            u.s[2 * i]     = f2bf(v.x);
            u.s[2 * i + 1] = f2bf(v.y);
        }
        s_af2[(jj << 6) + (e << 1)] = u.v;
    }
    // ks=1 half: {W1[...][8], W1[...][9], b1, 0...}
    for (int ii = tid; ii < DH * 32; ii += BLOCK) {
        const int jj = ii >> 5, e = ii & 31;
        const float2 v = *(const float2*)(W1 + (size_t)(e * DH + jj) * DIN + 8);
        const float bb = b1[e * DH + jj];
        BFU u;
        u.s[0] = f2bf(v.x); u.s[1] = f2bf(v.y); u.s[2] = f2bf(bb);
        u.s[3] = 0; u.s[4] = 0; u.s[5] = 0; u.s[6] = 0; u.s[7] = 0;
        s_af2[(jj << 6) + (e << 1) + 1] = u.v;
    }
    for (int idx = tid; idx < DH * 32; idx += BLOCK) {
        const int jj = idx >> 5, rem = idx & 31;
        const int hf = rem >> 4, q = rem & 15;
        const int p = (q & 3) + 8 * (q >> 2) + 4 * hf;   // expert of C-reg q in half hf
        s_w2c[idx] = W2[p * DH + jj];
    }
    if (tid < 64) {
        const int m = tid & 31, kb = (tid >> 5) * 8;
        BFU u;
#pragma unroll
        for (int j = 0; j < 8; ++j) {
            const int kk = kb + j;
            u.s[j] = f2bf(kk < DIN ? proto[m * DIN + kk] : 0.f);  // slot 10 = 0
        }
        s_pf[tid] = u.v;
    }
    if (tid < 16) {
        const int hf = tid >> 3, i = tid & 7;
        const int q0 = 2 * i, q1 = 2 * i + 1;
        const int p0 = (q0 & 3) + 8 * (q0 >> 2) + 4 * hf;
        const int p1 = (q1 & 3) + 8 * (q1 >> 2) + 4 * hf;
        float s0 = 0.f, s1 = 0.f;
#pragma unroll
        for (int i2 = 0; i2 < DIN; ++i2) {
            const float a = proto[p0 * DIN + i2]; s0 = fmaf(a, a, s0);
            const float b = proto[p1 * DIN + i2]; s1 = fmaf(b, b, s1);
        }
        s_gkp[tid] = make_float2(s0 * LOG2E_SQ, s1 * LOG2E_SQ);
        s_b2p[tid] = make_float2(b2[p0], b2[p1]);
    }
    __syncthreads();

    const bf16x8 pfrag = s_pf[lane];
    const f32x16 kZero = ZERO16;
    const int aoff = (col << 1) + half;   // lane's A-frag slot within each jj block

    // ---- per-tile state (statically indexed only) ----
    bf16x8 xfrag[TPW];
    float  xn2[TPW];     // ||x||^2 * (log2 e)^2
    v2f    pa[TPW][8];   // per-lane pred partials (b2 pre-loaded), gate-reg-ordered

#pragma unroll
    for (int t = 0; t < TPW; ++t) {
        // B-frag: x_ext[rr][half*8 .. +7]; slot 10 = 1.0 (bias)
        float xe[8];
        if (half == 0) {
#pragma unroll
            for (int i = 0; i < 4; ++i) {
                xe[2 * i] = xld[t][i].x; xe[2 * i + 1] = xld[t][i].y;
            }
        } else {
            xe[0] = xld[t][0].x; xe[1] = xld[t][0].y; xe[2] = 1.f;
            xe[3] = 0.f; xe[4] = 0.f; xe[5] = 0.f; xe[6] = 0.f; xe[7] = 0.f;
        }
        BFU xu;
#pragma unroll
        for (int j = 0; j < 8; ++j) xu.s[j] = f2bf(xe[j]);
        xfrag[t] = xu.v;

        // ||x||^2 (fp32): half0 sums its 8, half1 only x[8],x[9]; pre-scale by c^2
        float part;
        if (half == 0) {
            part = 0.f;
#pragma unroll
            for (int j = 0; j < 8; ++j) part = fmaf(xe[j], xe[j], part);
        } else {
            part = fmaf(xe[0], xe[0], xe[1] * xe[1]);
        }
        xn2[t] = (part + __shfl_xor(part, 32)) * LOG2E_SQ;

#pragma unroll
        for (int i = 0; i < 8; ++i) {
            const float2 bp = s_b2p[half * 8 + i];
            pa[t][i] = v2f{bp.x, bp.y};
        }
    }

    // ---- dense main loop: MFMA jj = hidden unit jj of ALL 32 experts (e(m)=m) ----
    const float4* w2base = (const float4*)s_w2c + (half << 2);
#pragma unroll 2
    for (int jj = 0; jj < DH; ++jj) {
        const bf16x8 a = s_af2[(jj << 6) + aoff];
        const float4* w4 = w2base + (jj << 3);
        const float4 w0 = w4[0], w1v = w4[1], w2v = w4[2], w3v = w4[3];

#pragma unroll
        for (int t = 0; t < TPW; ++t) {
            const f32x16 c = __builtin_amdgcn_mfma_f32_32x32x16_bf16(a, xfrag[t], kZero, 0, 0, 0);
            v2f r;
            r = __builtin_elementwise_max(v2f{c[0],  c[1]},  v2f{0.f, 0.f});
            pa[t][0] = __builtin_elementwise_fma(r, v2f{w0.x,  w0.y},  pa[t][0]);
            r = __builtin_elementwise_max(v2f{c[2],  c[3]},  v2f{0.f, 0.f});
            pa[t][1] = __builtin_elementwise_fma(r, v2f{w0.z,  w0.w},  pa[t][1]);
            r = __builtin_elementwise_max(v2f{c[4],  c[5]},  v2f{0.f, 0.f});
            pa[t][2] = __builtin_elementwise_fma(r, v2f{w1v.x, w1v.y}, pa[t][2]);
            r = __builtin_elementwise_max(v2f{c[6],  c[7]},  v2f{0.f, 0.f});
            pa[t][3] = __builtin_elementwise_fma(r, v2f{w1v.z, w1v.w}, pa[t][3]);
            r = __builtin_elementwise_max(v2f{c[8],  c[9]},  v2f{0.f, 0.f});
            pa[t][4] = __builtin_elementwise_fma(r, v2f{w2v.x, w2v.y}, pa[t][4]);
            r = __builtin_elementwise_max(v2f{c[10], c[11]}, v2f{0.f, 0.f});
            pa[t][5] = __builtin_elementwise_fma(r, v2f{w2v.z, w2v.w}, pa[t][5]);
            r = __builtin_elementwise_max(v2f{c[12], c[13]}, v2f{0.f, 0.f});
            pa[t][6] = __builtin_elementwise_fma(r, v2f{w3v.x, w3v.y}, pa[t][6]);
            r = __builtin_elementwise_max(v2f{c[14], c[15]}, v2f{0.f, 0.f});
            pa[t][7] = __builtin_elementwise_fma(r, v2f{w3v.z, w3v.w}, pa[t][7]);
        }
    }

    // ---- deferred gating (pk-paired) + combine + write (both tiles) ----
    const float2* gkp = s_gkp + half * 8;
    const v2f negc = {NEG2_LOG2E_SQ, NEG2_LOG2E_SQ};
#pragma unroll
    for (int t = 0; t < TPW; ++t) {
        const f32x16 dg = __builtin_amdgcn_mfma_f32_32x32x16_bf16(pfrag, xfrag[t], kZero, 0, 0, 0);
        const v2f xnv = {xn2[t], xn2[t]};
        v2f dsv = {0.f, 0.f}, nsv = {0.f, 0.f};
#pragma unroll
        for (int i = 0; i < 8; ++i) {
            const float2 gg = gkp[i];
            v2f d2 = v2f{gg.x, gg.y} + xnv;                                  // v_pk_add
            d2 = __builtin_elementwise_fma(v2f{dg[2 * i], dg[2 * i + 1]}, negc, d2); // v_pk_fma
            d2 = __builtin_elementwise_max(d2, v2f{0.f, 0.f});
            const float g0 = __builtin_amdgcn_exp2f(-__fsqrt_rn(d2.x));
            const float g1 = __builtin_amdgcn_exp2f(-__fsqrt_rn(d2.y));
            const v2f g = {g0, g1};
            dsv += g;                                                        // v_pk_add
            nsv = __builtin_elementwise_fma(g, pa[t][i], nsv);               // v_pk_fma
        }
        const float ns = nsv.x + nsv.y;
        const float ds = dsv.x + dsv.y;
        const float nst = ns + __shfl_xor(ns, 32);
        const float dst = ds + __shfl_xor(ds, 32);
        if (half == 0 && row[t] < B) out[row[t]] = nst * __builtin_amdgcn_rcpf(dst);
    }
}

extern "C" void kernel_launch(void* const* d_in, const int* in_sizes, int n_in,
                              void* d_out, int out_size, void* d_ws, size_t ws_size,
                              hipStream_t stream) {
    const float* x     = (const float*)d_in[0];
    const float* W1    = (const float*)d_in[1];
    const float* b1    = (const float*)d_in[2];
    const float* W2    = (const float*)d_in[3];
    const float* b2    = (const float*)d_in[4];
    const float* proto = (const float*)d_in[5];
    float* out = (float*)d_out;

    const int B = out_size;                    // D_OUT = 1
    const int rows_per_block = WPB * TPW * 32; // 16 waves x 2 tiles x 32 rows = 1024
    const int grid = (B + rows_per_block - 1) / rows_per_block;
    hipLaunchKernelGGL(moe_kernel, dim3(grid), dim3(BLOCK), 0, stream,
                       x, W1, b1, W2, b2, proto, out, B);
}

// Round 4
// 85.293 us; speedup vs baseline: 1.1185x; 1.0168x over previous
//
#include <hip/hip_runtime.h>

// PiecewiseSparseMLP: B=262144 rows, K=32 experts (10 -> 20 -> 1), distance-softmax gating.
// Round 20: R19 structure (dense hidden packing, gate-aligned C regs, deferred pk'd
// gating, exp2/rcp folds, hoisted x loads, static-ks build) + expansion-type trims:
//   - __fsqrt_rn -> __builtin_amdgcn_sqrtf: raw v_sqrt_f32 (1 instr) instead of the
//     correctly-rounded expansion (~6 instrs). 64 sqrts/wave -> ~300 instrs saved.
//   - software RNE f2bf -> v_cvt_pk_bf16_f32 inline asm (2 values/instr, HW RNE,
//     bit-identical): ~96 conversions/thread (W1/b1 build + xfrag) at ~5 VALU each
//     -> ~48 cvt_pk. Constant slots (bias 1.0, zeros) written as literals.
//   - xn2 squares via v_pk_fma pairs.
// Main loop untouched: at its 1.5-instr/elem floor (no packed f32 max on CDNA4).
// Proven-stable: launch_bounds(1024,4)=cap 128, `unroll 2`, statically indexed arrays
// only (R8/R9/R15 spill lessons). grid=256.

#define KX 32
#define DIN 10
#define DH 20
#define BLOCK 1024
#define WPB 16  // waves per block
#define TPW 2   // row-tiles per wave (interleaved)

#define LOG2E_SQ 2.0813689810056077f
#define NEG2_LOG2E_SQ -4.1627379620112154f

typedef short bf16x8 __attribute__((ext_vector_type(8)));
typedef float f32x16 __attribute__((ext_vector_type(16)));
typedef float v2f    __attribute__((ext_vector_type(2)));

#define ZERO16 {0.f,0.f,0.f,0.f, 0.f,0.f,0.f,0.f, 0.f,0.f,0.f,0.f, 0.f,0.f,0.f,0.f}

// 2x f32 -> packed bf16 pair (RNE), single v_cvt_pk_bf16_f32. No builtin on gfx950;
// non-volatile asm so it CSEs/schedules freely (pure function).
__device__ inline unsigned int cvt_pk_bf16(float lo, float hi) {
    unsigned int r;
    asm("v_cvt_pk_bf16_f32 %0, %1, %2" : "=v"(r) : "v"(lo), "v"(hi));
    return r;
}

union BFU { bf16x8 v; unsigned short s[8]; unsigned int w[4]; };

__global__ __launch_bounds__(BLOCK, 4) void moe_kernel(
    const float* __restrict__ x,      // [B,10]
    const float* __restrict__ W1,     // [32,20,10]
    const float* __restrict__ b1,     // [32,20]
    const float* __restrict__ W2,     // [32,1,20]
    const float* __restrict__ b2,     // [32]
    const float* __restrict__ proto,  // [32,10]
    float* __restrict__ out,          // [B]
    int B)
{
    // A-frags: [jj][e*2 + ks] -> W1[e][jj][ks*8..+7] (k=10 slot = b1, rest 0). 20 KB.
    __shared__ bf16x8 s_af2[DH * 64];
    // W2 in C-reg order: [jj][hf*16 + q] = W2[p(q,hf)][jj]. 2.5 KB, 16B-aligned.
    __shared__ __attribute__((aligned(16))) float s_w2c[DH * 32];
    __shared__ bf16x8 s_pf[64];        // proto A-frag (1 KB)
    __shared__ float2 s_gkp[16];       // ||proto||^2*(log2e)^2 PAIRS, [hf*8+i] order
    __shared__ float2 s_b2p[16];       // b2 pairs in [hf*8+i] order (pa init)

    const int tid  = threadIdx.x;
    const int lane = tid & 63;
    const int wave = tid >> 6;
    const int half = lane >> 5;   // k-slice for A/B frags; C-half for epilogue
    const int col  = lane & 31;

    // ---- issue x row loads FIRST (latency hides under the LDS table build) ----
    int    row[TPW];
    float2 xld[TPW][4];   // half0 uses all 4; half1 uses [0] only
#pragma unroll
    for (int t = 0; t < TPW; ++t) {
        row[t] = ((blockIdx.x * WPB + wave) * TPW + t) * 32 + col;
        const int rr = (row[t] < B) ? row[t] : (B - 1);
        const float* xr = x + (size_t)rr * DIN;
        if (half == 0) {
#pragma unroll
            for (int i = 0; i < 4; ++i) xld[t][i] = *(const float2*)(xr + 2 * i);
        } else {
            xld[t][0] = *(const float2*)(xr + 8);
        }
    }

    // ---- build LDS tables (shared by all 16 waves) ----
    // ks=0 half of each A-frag pair: 8 contiguous floats, 4x cvt_pk.
    for (int ii = tid; ii < DH * 32; ii += BLOCK) {
        const int jj = ii >> 5, e = ii & 31;
        const float* wr = W1 + (size_t)(e * DH + jj) * DIN;
        BFU u;
#pragma unroll
        for (int i = 0; i < 4; ++i) {
            const float2 v = *(const float2*)(wr + 2 * i);
            u.w[i] = cvt_pk_bf16(v.x, v.y);
        }
        s_af2[(jj << 6) + (e << 1)] = u.v;
    }
    // ks=1 half: {W1[...][8], W1[...][9], b1, 0...}
    for (int ii = tid; ii < DH * 32; ii += BLOCK) {
        const int jj = ii >> 5, e = ii & 31;
        const float2 v = *(const float2*)(W1 + (size_t)(e * DH + jj) * DIN + 8);
        const float bb = b1[e * DH + jj];
        BFU u;
        u.w[0] = cvt_pk_bf16(v.x, v.y);
        u.w[1] = cvt_pk_bf16(bb, 0.f);
        u.w[2] = 0u; u.w[3] = 0u;
        s_af2[(jj << 6) + (e << 1) + 1] = u.v;
    }
    for (int idx = tid; idx < DH * 32; idx += BLOCK) {
        const int jj = idx >> 5, rem = idx & 31;
        const int hf = rem >> 4, q = rem & 15;
        const int p = (q & 3) + 8 * (q >> 2) + 4 * hf;   // expert of C-reg q in half hf
        s_w2c[idx] = W2[p * DH + jj];
    }
    if (tid < 64) {
        const int m = tid & 31;
        BFU u;
        if (tid < 32) {                 // ks=0 slice: proto[m][0..7]
            const float* pr = proto + m * DIN;
#pragma unroll
            for (int i = 0; i < 4; ++i) {
                const float2 v = *(const float2*)(pr + 2 * i);
                u.w[i] = cvt_pk_bf16(v.x, v.y);
            }
        } else {                        // ks=1 slice: proto[m][8..9], pad 0 (slot 10 = 0)
            const float2 v = *(const float2*)(proto + m * DIN + 8);
            u.w[0] = cvt_pk_bf16(v.x, v.y);
            u.w[1] = 0u; u.w[2] = 0u; u.w[3] = 0u;
        }
        s_pf[tid] = u.v;
    }
    if (tid < 16) {
        const int hf = tid >> 3, i = tid & 7;
        const int q0 = 2 * i, q1 = 2 * i + 1;
        const int p0 = (q0 & 3) + 8 * (q0 >> 2) + 4 * hf;
        const int p1 = (q1 & 3) + 8 * (q1 >> 2) + 4 * hf;
        float s0 = 0.f, s1 = 0.f;
#pragma unroll
        for (int i2 = 0; i2 < DIN; ++i2) {
            const float a = proto[p0 * DIN + i2]; s0 = fmaf(a, a, s0);
            const float b = proto[p1 * DIN + i2]; s1 = fmaf(b, b, s1);
        }
        s_gkp[tid] = make_float2(s0 * LOG2E_SQ, s1 * LOG2E_SQ);
        s_b2p[tid] = make_float2(b2[p0], b2[p1]);
    }
    __syncthreads();

    const bf16x8 pfrag = s_pf[lane];
    const f32x16 kZero = ZERO16;
    const int aoff = (col << 1) + half;   // lane's A-frag slot within each jj block

    // ---- per-tile state (statically indexed only) ----
    bf16x8 xfrag[TPW];
    float  xn2[TPW];     // ||x||^2 * (log2 e)^2
    v2f    pa[TPW][8];   // per-lane pred partials (b2 pre-loaded), gate-reg-ordered

#pragma unroll
    for (int t = 0; t < TPW; ++t) {
        BFU xu;
        v2f sq = {0.f, 0.f};
        float part;
        if (half == 0) {
            // x_ext[rr][0..7]
#pragma unroll
            for (int i = 0; i < 4; ++i) {
                const v2f v = {xld[t][i].x, xld[t][i].y};
                xu.w[i] = cvt_pk_bf16(v.x, v.y);
                sq = __builtin_elementwise_fma(v, v, sq);   // v_pk_fma
            }
            part = sq.x + sq.y;
        } else {
            // x_ext[rr][8..15] = {x8, x9, 1(bias), 0...}
            const float x8 = xld[t][0].x, x9 = xld[t][0].y;
            xu.w[0] = cvt_pk_bf16(x8, x9);
            xu.w[1] = 0x3f80u;            // {bf16(1.0), bf16(0)}
            xu.w[2] = 0u; xu.w[3] = 0u;
            part = fmaf(x8, x8, x9 * x9);
        }
        xfrag[t] = xu.v;
        xn2[t] = (part + __shfl_xor(part, 32)) * LOG2E_SQ;

#pragma unroll
        for (int i = 0; i < 8; ++i) {
            const float2 bp = s_b2p[half * 8 + i];
            pa[t][i] = v2f{bp.x, bp.y};
        }
    }

    // ---- dense main loop: MFMA jj = hidden unit jj of ALL 32 experts (e(m)=m) ----
    const float4* w2base = (const float4*)s_w2c + (half << 2);
#pragma unroll 2
    for (int jj = 0; jj < DH; ++jj) {
        const bf16x8 a = s_af2[(jj << 6) + aoff];
        const float4* w4 = w2base + (jj << 3);
        const float4 w0 = w4[0], w1v = w4[1], w2v = w4[2], w3v = w4[3];

#pragma unroll
        for (int t = 0; t < TPW; ++t) {
            const f32x16 c = __builtin_amdgcn_mfma_f32_32x32x16_bf16(a, xfrag[t], kZero, 0, 0, 0);
            v2f r;
            r = __builtin_elementwise_max(v2f{c[0],  c[1]},  v2f{0.f, 0.f});
            pa[t][0] = __builtin_elementwise_fma(r, v2f{w0.x,  w0.y},  pa[t][0]);
            r = __builtin_elementwise_max(v2f{c[2],  c[3]},  v2f{0.f, 0.f});
            pa[t][1] = __builtin_elementwise_fma(r, v2f{w0.z,  w0.w},  pa[t][1]);
            r = __builtin_elementwise_max(v2f{c[4],  c[5]},  v2f{0.f, 0.f});
            pa[t][2] = __builtin_elementwise_fma(r, v2f{w1v.x, w1v.y}, pa[t][2]);
            r = __builtin_elementwise_max(v2f{c[6],  c[7]},  v2f{0.f, 0.f});
            pa[t][3] = __builtin_elementwise_fma(r, v2f{w1v.z, w1v.w}, pa[t][3]);
            r = __builtin_elementwise_max(v2f{c[8],  c[9]},  v2f{0.f, 0.f});
            pa[t][4] = __builtin_elementwise_fma(r, v2f{w2v.x, w2v.y}, pa[t][4]);
            r = __builtin_elementwise_max(v2f{c[10], c[11]}, v2f{0.f, 0.f});
            pa[t][5] = __builtin_elementwise_fma(r, v2f{w2v.z, w2v.w}, pa[t][5]);
            r = __builtin_elementwise_max(v2f{c[12], c[13]}, v2f{0.f, 0.f});
            pa[t][6] = __builtin_elementwise_fma(r, v2f{w3v.x, w3v.y}, pa[t][6]);
            r = __builtin_elementwise_max(v2f{c[14], c[15]}, v2f{0.f, 0.f});
            pa[t][7] = __builtin_elementwise_fma(r, v2f{w3v.z, w3v.w}, pa[t][7]);
        }
    }

    // ---- deferred gating (pk-paired) + combine + write (both tiles) ----
    const float2* gkp = s_gkp + half * 8;
    const v2f negc = {NEG2_LOG2E_SQ, NEG2_LOG2E_SQ};
#pragma unroll
    for (int t = 0; t < TPW; ++t) {
        const f32x16 dg = __builtin_amdgcn_mfma_f32_32x32x16_bf16(pfrag, xfrag[t], kZero, 0, 0, 0);
        const v2f xnv = {xn2[t], xn2[t]};
        v2f dsv = {0.f, 0.f}, nsv = {0.f, 0.f};
#pragma unroll
        for (int i = 0; i < 8; ++i) {
            const float2 gg = gkp[i];
            v2f d2 = v2f{gg.x, gg.y} + xnv;                                  // v_pk_add
            d2 = __builtin_elementwise_fma(v2f{dg[2 * i], dg[2 * i + 1]}, negc, d2); // v_pk_fma
            d2 = __builtin_elementwise_max(d2, v2f{0.f, 0.f});
            const float g0 = __builtin_amdgcn_exp2f(-__builtin_amdgcn_sqrtf(d2.x));
            const float g1 = __builtin_amdgcn_exp2f(-__builtin_amdgcn_sqrtf(d2.y));
            const v2f g = {g0, g1};
            dsv += g;                                                        // v_pk_add
            nsv = __builtin_elementwise_fma(g, pa[t][i], nsv);               // v_pk_fma
        }
        const float ns = nsv.x + nsv.y;
        const float ds = dsv.x + dsv.y;
        const float nst = ns + __shfl_xor(ns, 32);
        const float dst = ds + __shfl_xor(ds, 32);
        if (half == 0 && row[t] < B) out[row[t]] = nst * __builtin_amdgcn_rcpf(dst);
    }
}

extern "C" void kernel_launch(void* const* d_in, const int* in_sizes, int n_in,
                              void* d_out, int out_size, void* d_ws, size_t ws_size,
                              hipStream_t stream) {
    const float* x     = (const float*)d_in[0];
    const float* W1    = (const float*)d_in[1];
    const float* b1    = (const float*)d_in[2];
    const float* W2    = (const float*)d_in[3];
    const float* b2    = (const float*)d_in[4];
    const float* proto = (const float*)d_in[5];
    float* out = (float*)d_out;

    const int B = out_size;                    // D_OUT = 1
    const int rows_per_block = WPB * TPW * 32; // 16 waves x 2 tiles x 32 rows = 1024
    const int grid = (B + rows_per_block - 1) / rows_per_block;
    hipLaunchKernelGGL(moe_kernel, dim3(grid), dim3(BLOCK), 0, stream,
                       x, W1, b1, W2, b2, proto, out, B);
}